// Round 19
// baseline (426.112 us; speedup 1.0000x reference)
//
#include <hip/hip_runtime.h>

typedef unsigned short u16;
typedef unsigned int u32;

using f32x4  = __attribute__((ext_vector_type(4))) float;
using f32x16 = __attribute__((ext_vector_type(16))) float;
using bf16x8 = __attribute__((ext_vector_type(8))) __bf16;

#define S_LEN 2048
#define HID_DIM 4096
#define NH 32
#define NKV 8
#define HD 128
#define QKVN 6144

__device__ __forceinline__ u16 f2b(float f) {
  union { float f; u32 u; } v; v.f = f;
  u32 r = (v.u + 0x7FFFu + ((v.u >> 16) & 1u)) >> 16;
  return (u16)r;
}
__device__ __forceinline__ float b2f(u16 b) {
  union { u32 u; float f; } v; v.u = ((u32)b) << 16;
  return v.f;
}

__device__ __forceinline__ u32 cvtpk_bf16(float lo, float hi) {
  u32 r;
  asm("v_cvt_pk_bf16_f32 %0, %1, %2" : "=v"(r) : "v"(lo), "v"(hi));
  return r;
}
__device__ __forceinline__ void plane_swap(u32& a, u32& b) {
  asm volatile("v_permlane32_swap_b32 %0, %1" : "+v"(a), "+v"(b));
}

#define AS1 __attribute__((address_space(1)))
#define AS3 __attribute__((address_space(3)))
__device__ __forceinline__ void gl_lds16(const u16* g, u16* l) {
  __builtin_amdgcn_global_load_lds((const AS1 u32*)g, (AS3 u32*)l, 16, 0, 0);
}

#define SBAR  __builtin_amdgcn_s_barrier()
#define SCHED0 __builtin_amdgcn_sched_barrier(0)
#define LGKM0 do { asm volatile("s_waitcnt lgkmcnt(0)" ::: "memory"); SCHED0; } while (0)
#define PRIO1 __builtin_amdgcn_s_setprio(1)
#define PRIO0 __builtin_amdgcn_s_setprio(0)

template <int N> __device__ __forceinline__ void waitv() {
  if constexpr (N == 0)      asm volatile("s_waitcnt vmcnt(0)" ::: "memory");
  else if constexpr (N == 2) asm volatile("s_waitcnt vmcnt(2)" ::: "memory");
  else if constexpr (N == 4) asm volatile("s_waitcnt vmcnt(4)" ::: "memory");
  else                       asm volatile("s_waitcnt vmcnt(0)" ::: "memory");
  SCHED0;
}

// ------ fused fp32 -> bf16 cast; weights go DIRECTLY to MFMA frag-order -----
// frag-order for B[n][k] (K=4096, 128 k-chunks of 32):
//   F = n>>4, lr = n&15, c = k>>5, lg = (k>>3)&3, e = k&7
//   off = ((F*128 + c)*4 + lg)*128 + lr*8 + e
#define X4T 2097152
#define Q4T 4194304
#define K4T 1048576
#define TOT4 (X4T + Q4T + K4T + K4T + Q4T)
__device__ __forceinline__ void frag_store(u16* base, int n, int k0, uint2 o) {
  int F = n >> 4, lr = n & 15, c = k0 >> 5, lg = (k0 >> 3) & 3, e0 = k0 & 7;
  *(uint2*)&base[((((size_t)F * 128 + c) * 4 + lg) * 128) + lr * 8 + e0] = o;
}
__global__ void cast_all(const float* __restrict__ x,  const float* __restrict__ wq,
                         const float* __restrict__ wk, const float* __restrict__ wv,
                         const float* __restrict__ wo,
                         u16* __restrict__ xb, u16* __restrict__ wqkvF,
                         u16* __restrict__ woF) {
  int i = blockIdx.x * blockDim.x + threadIdx.x;
  int stride = gridDim.x * blockDim.x;
  for (; i < TOT4; i += stride) {
    const float* src;
    int off, mode, nbias = 0;
    u16* base;
    if (i < X4T)                     { src = x;  off = i;                     mode = 0; base = xb; }
    else if (i < X4T + Q4T)          { src = wq; off = i - X4T;               mode = 1; base = wqkvF; }
    else if (i < X4T + Q4T + K4T)    { src = wk; off = i - X4T - Q4T;         mode = 1; base = wqkvF; nbias = 4096; }
    else if (i < X4T + Q4T + 2*K4T)  { src = wv; off = i - X4T - Q4T - K4T;   mode = 1; base = wqkvF; nbias = 5120; }
    else                             { src = wo; off = i - X4T - Q4T - 2*K4T; mode = 1; base = woF; }
    float4 v = ((const float4*)src)[off];
    uint2 o;
    o.x = (u32)f2b(v.x) | ((u32)f2b(v.y) << 16);
    o.y = (u32)f2b(v.z) | ((u32)f2b(v.w) << 16);
    if (mode == 0) {
      ((uint2*)base)[off] = o;
    } else {
      int n = (off >> 10) + nbias;       // off / (K/4), K=4096
      int k0 = (off & 1023) * 4;
      frag_store(base, n, k0, o);
    }
  }
}

// STAGE: CH chunks of 8KB (512 thr x 16B), XOR-swizzled source, linear LDS dest
#define STAGE(DST, SRC, CH, LDK)                                   \
  _Pragma("unroll") for (int c = 0; c < (CH); ++c) {               \
    int d_ = c * 8192 + tid * 16;                                  \
    int rw_ = d_ >> 7;                                             \
    int cb_ = (d_ & 127) ^ ((rw_ & 7) << 4);                       \
    gl_lds16((SRC) + (size_t)rw_ * (LDK) + (cb_ >> 1), (DST) + (d_ >> 1)); \
  }

// ============ GEMM: A via LDS, B via frag-order GLOBAL (no LDS for B) ======
// BM=128, 512 threads = 8 waves (2M x 4N), per-wave 64 x WN; 2 blocks/CU.
// B fragments load lane-contiguous 16B direct from the frag-order weight
// buffer (L2-served, no sync needed - pure dataflow). LDS holds only A
// (32 KB dbuf): per-tile LDS traffic drops ~150KB -> ~80KB (the r18-measured
// invariant ~4400cy/tile was LDS-service-bound).
#define RDA(ABUF, KS)                                                         \
  _Pragma("unroll") for (int mm = 0; mm < 4; ++mm)                            \
    af[mm][KS] = *(const bf16x8*)((const char*)(ABUF) +                       \
      (wmo + mm * 16 + lr) * 128 + (((((KS) << 2) | lg) ^ lr7) << 4));

#define RDBG(T, KS)                                                           \
  _Pragma("unroll") for (int nn = 0; nn < NF; ++nn)                           \
    bfr[nn][KS] = *(const bf16x8*)&BF[((((size_t)(nF0 + nn) * (K >> 5) +      \
      ((T) * 2 + (KS))) * 4 + lg) << 7) + lr * 8];

#define MFMA_Q(KS)                                                            \
  _Pragma("unroll") for (int mm = 0; mm < 4; ++mm)                            \
  _Pragma("unroll") for (int nn = 0; nn < NF; ++nn)                           \
    acc[mm][nn] = __builtin_amdgcn_mfma_f32_16x16x32_bf16(                    \
        af[mm][KS], bfr[nn][KS], acc[mm][nn], 0, 0, 0);

template <int BN, int WN, int CBF>
__global__ __launch_bounds__(512, 2) void gemm_bg(
    const u16* __restrict__ A, const u16* __restrict__ BF, void* __restrict__ Cout,
    int M, int N, int K)
{
  constexpr int NF = WN / 16;
  constexpr int BM = 128;
  constexpr int LA = 2;             // A-tile gl_lds chunks (128x64x2B / 8KB)
  extern __shared__ __align__(16) u16 smem[];
  u16* const As0 = smem;            // 2 x 8192 u16

  const int tid  = threadIdx.x;
  const int lane = tid & 63;
  const int wave = tid >> 6;
  const int lr  = lane & 15;
  const int lg  = lane >> 4;
  const int lr7 = lane & 7;

  const int nbx = N / BN;
  const int bid = blockIdx.x;
  const int cpx = gridDim.x >> 3;
  const int swz = (bid & 7) * cpx + (bid >> 3);   // XCD swizzle (grid%8==0)
  const int bm = (swz / nbx) * BM;
  const int bn = (swz % nbx) * BN;
  const int wmo = (wave >> 2) * 64;
  const int wno = (wave & 3) * WN;
  const int nF0 = (bn + wno) >> 4;  // first B-fragment row-group index

  const int NT = K >> 6;

  f32x4 acc[4][NF] = {};
  bf16x8 af[4][2], bfr[NF][2];

  const u16* aP = A + (size_t)bm * K;

  // prologue: stage A tiles 0 and 1
  STAGE(As0,        aP,      LA, K);
  STAGE(As0 + 8192, aP + 64, LA, K);
  waitv<2>();         // A(0) resident; A(1) in flight
  SBAR; SCHED0;

  for (int t = 0; t < NT; ++t) {
    const int buf = t & 1;
    const u16* ab = As0 + buf * 8192;
    const bool st = (t + 2 < NT);

    // ks0: A from LDS, B direct from global frag-order
    RDA(ab, 0); RDBG(t, 0);
    LGKM0;
    PRIO1; MFMA_Q(0); PRIO0;
    RDA(ab, 1); RDBG(t, 1);
    LGKM0;
    SBAR;              // all waves drained A reads of this buffer

    if (st) { STAGE(As0 + buf * 8192, aP + (size_t)(t + 2) * 64, LA, K); }
    PRIO1; MFMA_Q(1); PRIO0;
    if (t + 1 < NT) {
      if (st) waitv<2>(); else waitv<0>();
    }
    SBAR; SCHED0;
  }

  // epilogue
#pragma unroll
  for (int m = 0; m < 4; ++m)
#pragma unroll
    for (int j = 0; j < 4; ++j) {
      int row = bm + wmo + m * 16 + lg * 4 + j;
      size_t base = (size_t)row * N + bn + wno + lr;
      if constexpr (CBF) {
        u16* C = (u16*)Cout;
#pragma unroll
        for (int nn = 0; nn < NF; ++nn) C[base + nn * 16] = f2b(acc[m][nn][j]);
      } else {
        float* C = (float*)Cout;
#pragma unroll
        for (int nn = 0; nn < NF; ++nn) C[base + nn * 16] = acc[m][nn][j];
      }
    }
}

// ---------------- RoPE; frag=0 -> [nh][S][D], frag=1 -> frag-order ----------
__global__ void rope_qk(const u16* __restrict__ qkv, u16* __restrict__ dst,
                        int col_off, float scale, int frag) {
  int idx = blockIdx.x * blockDim.x + threadIdx.x;
  int i = idx & 63;
  int s = (idx >> 6) & (S_LEN - 1);
  int h = idx >> 17;
  const u16* row = qkv + (size_t)s * QKVN + col_off + h * HD;
  float a = b2f(row[i]);
  float b = b2f(row[i + 64]);
  float invf = __expf(-(float)i * 0.14391156831212787f);  // ln(10000)/64
  float f = (float)s * invf;
  float sn, cs;
  sincosf(f, &sn, &cs);
  float o1 = (a * cs - b * sn) * scale;
  float o2 = (b * cs + a * sn) * scale;
  if (frag) {
    int qt = h * 64 + (s >> 5);
    int qq = s & 31;
    int i2 = i + 64;
    dst[((qt * 8 + (i  >> 4)) * 2 + ((i  >> 3) & 1)) * 256 + qq * 8 + (i  & 7)] = f2b(o1);
    dst[((qt * 8 + (i2 >> 4)) * 2 + ((i2 >> 3) & 1)) * 256 + qq * 8 + (i2 & 7)] = f2b(o2);
  } else {
    u16* orow = dst + ((size_t)h * S_LEN + s) * HD;
    orow[i]      = f2b(o1);
    orow[i + 64] = f2b(o2);
  }
}

// ---------------- V frag-order pack ----------------
__global__ __launch_bounds__(256) void vf_pack(const u16* __restrict__ qkv,
                                               u16* __restrict__ VF) {
  __shared__ u16 vlds[32][136];
  const int bid = blockIdx.x;          // kv*64 + t
  const int kv = bid >> 6, t = bid & 63;
  const int tid = threadIdx.x;
  const int r = tid >> 3, d0 = (tid & 7) * 16;
  const u16* src = qkv + (size_t)(t * 32 + r) * QKVN + 5120 + kv * HD + d0;
  *(bf16x8*)&vlds[r][d0]     = *(const bf16x8*)src;
  *(bf16x8*)&vlds[r][d0 + 8] = *(const bf16x8*)(src + 8);
  __syncthreads();
  u16* outt = VF + (size_t)bid * 4096;
#pragma unroll
  for (int g = 0; g < 2; ++g) {
    int G = tid + g * 256;
    int q = G & 31, dt = (G >> 5) & 3, hi2 = (G >> 7) & 1, kc = G >> 8;
    union { u16 u[8]; uint4 v; } o;
#pragma unroll
    for (int e = 0; e < 8; ++e)
      o.u[e] = vlds[kc * 16 + hi2 * 8 + e][dt * 32 + q];
    *(uint4*)&outt[G * 8] = o.v;
  }
}

// ---------------- flash attention: all-frag-order (r12-verified) ----------
__global__ __launch_bounds__(256, 2) void attn_fwd(
    const u16* __restrict__ QF,  // frag-order Q (pre-scaled log2(e)/sqrt(D))
    const u16* __restrict__ KF,  // frag-order K
    const u16* __restrict__ VF,  // frag-order V
    u16* __restrict__ Out)       // [S][H*D]
{
  const int tid  = threadIdx.x;
  const int lane = tid & 63;
  const int wv   = tid >> 6;
  const int q31  = lane & 31;
  const int hi   = lane >> 5;
  const int bid  = blockIdx.x;
  const int kvh  = bid & 7;
  const int qi   = 63 - (bid >> 3);       // heavy blocks first
  const int q0   = qi * 32;
  const int h    = kvh * 4 + wv;
  const int nt   = qi + 1;

  const u16* kbase = KF + (size_t)kvh * 64 * 4096 + hi * 256  + q31 * 8;
  const u16* vbase = VF + (size_t)kvh * 64 * 4096 + hi * 1024 + q31 * 8;

  bf16x8 qf[8];
  const u16* qfp = QF + (size_t)(h * 64 + qi) * 4096 + hi * 256 + q31 * 8;
#pragma unroll
  for (int dc = 0; dc < 8; ++dc)
    qf[dc] = *(const bf16x8*)(qfp + dc * 512);

  f32x16 o0 = {}, o1 = {}, o2 = {}, o3 = {};
  float m = -1e30f, lsum = 0.f;

  for (int t = 0; t < nt; ++t) {
    SBAR;

    bf16x8 kf[8];
    const u16* kfp = kbase + (size_t)t * 4096;
#pragma unroll
    for (int dc = 0; dc < 8; ++dc)
      kf[dc] = *(const bf16x8*)(kfp + dc * 512);

    bf16x8 vf[8];
    const u16* vfp = vbase + (size_t)t * 4096;
#pragma unroll
    for (int i = 0; i < 8; ++i)
      vf[i] = *(const bf16x8*)(vfp + (i & 1) * 2048 + (i >> 1) * 256);

    f32x16 st = {};
    PRIO1;
#pragma unroll
    for (int dc = 0; dc < 8; ++dc)
      st = __builtin_amdgcn_mfma_f32_32x32x16_bf16(kf[dc], qf[dc], st, 0, 0, 0);
    PRIO0;

    if (t == nt - 1) {
#pragma unroll
      for (int r = 0; r < 16; ++r) {
        int kk = (r & 3) + 8 * (r >> 2) + 4 * hi;
        if (kk > q31) st[r] = -1e30f;
      }
    }

    float a0 = fmaxf(st[0], st[1]),   a1 = fmaxf(st[2], st[3]);
    float a2 = fmaxf(st[4], st[5]),   a3 = fmaxf(st[6], st[7]);
    float a4 = fmaxf(st[8], st[9]),   a5 = fmaxf(st[10], st[11]);
    float a6 = fmaxf(st[12], st[13]), a7 = fmaxf(st[14], st[15]);
    a0 = fmaxf(a0, a1); a2 = fmaxf(a2, a3); a4 = fmaxf(a4, a5); a6 = fmaxf(a6, a7);
    float pmax = fmaxf(fmaxf(a0, a2), fmaxf(a4, a6));
    pmax = fmaxf(pmax, __shfl_xor(pmax, 32));

    if (__any(pmax > m + 8.f)) {
      float mn = fmaxf(m, pmax);
      float sf = exp2f(m - mn);
      m = mn;
      lsum *= sf;
#pragma unroll
      for (int r = 0; r < 16; ++r) { o0[r] *= sf; o1[r] *= sf; o2[r] *= sf; o3[r] *= sf; }
    }

    float ev[16];
#pragma unroll
    for (int r = 0; r < 16; ++r) ev[r] = exp2f(st[r] - m);
    float s0 = (ev[0] + ev[1]) + (ev[2] + ev[3]);
    float s1 = (ev[4] + ev[5]) + (ev[6] + ev[7]);
    float s2 = (ev[8] + ev[9]) + (ev[10] + ev[11]);
    float s3 = (ev[12] + ev[13]) + (ev[14] + ev[15]);
    float ps = (s0 + s1) + (s2 + s3);
    ps += __shfl_xor(ps, 32);
    lsum += ps;

    u32 c0 = cvtpk_bf16(ev[0],  ev[1]),  c1 = cvtpk_bf16(ev[2],  ev[3]);
    u32 c2 = cvtpk_bf16(ev[4],  ev[5]),  c3 = cvtpk_bf16(ev[6],  ev[7]);
    u32 c4 = cvtpk_bf16(ev[8],  ev[9]),  c5 = cvtpk_bf16(ev[10], ev[11]);
    u32 c6 = cvtpk_bf16(ev[12], ev[13]), c7 = cvtpk_bf16(ev[14], ev[15]);
    plane_swap(c0, c2);
    plane_swap(c1, c3);
    plane_swap(c4, c6);
    plane_swap(c5, c7);
    union { u32 u[4]; bf16x8 v; } pb0u, pb1u;
    pb0u.u[0] = c0; pb0u.u[1] = c1; pb0u.u[2] = c2; pb0u.u[3] = c3;
    pb1u.u[0] = c4; pb1u.u[1] = c5; pb1u.u[2] = c6; pb1u.u[3] = c7;

    PRIO1;
    o0 = __builtin_amdgcn_mfma_f32_32x32x16_bf16(vf[0], pb0u.v, o0, 0, 0, 0);
    o1 = __builtin_amdgcn_mfma_f32_32x32x16_bf16(vf[2], pb0u.v, o1, 0, 0, 0);
    o2 = __builtin_amdgcn_mfma_f32_32x32x16_bf16(vf[4], pb0u.v, o2, 0, 0, 0);
    o3 = __builtin_amdgcn_mfma_f32_32x32x16_bf16(vf[6], pb0u.v, o3, 0, 0, 0);
    o0 = __builtin_amdgcn_mfma_f32_32x32x16_bf16(vf[1], pb1u.v, o0, 0, 0, 0);
    o1 = __builtin_amdgcn_mfma_f32_32x32x16_bf16(vf[3], pb1u.v, o1, 0, 0, 0);
    o2 = __builtin_amdgcn_mfma_f32_32x32x16_bf16(vf[5], pb1u.v, o2, 0, 0, 0);
    o3 = __builtin_amdgcn_mfma_f32_32x32x16_bf16(vf[7], pb1u.v, o3, 0, 0, 0);
    PRIO0;
  }

  float inv = 1.0f / lsum;
  u16* orow = Out + (size_t)(q0 + q31) * (NH * HD) + h * HD;
#pragma unroll
  for (int dt = 0; dt < 4; ++dt) {
    const f32x16& oo = dt == 0 ? o0 : dt == 1 ? o1 : dt == 2 ? o2 : o3;
#pragma unroll
    for (int g = 0; g < 4; ++g) {
      ushort4 pk;
      pk.x = f2b(oo[g * 4 + 0] * inv);
      pk.y = f2b(oo[g * 4 + 1] * inv);
      pk.z = f2b(oo[g * 4 + 2] * inv);
      pk.w = f2b(oo[g * 4 + 3] * inv);
      *(ushort4*)&orow[dt * 32 + 8 * g + 4 * hi] = pk;
    }
  }
}

// ---------------- launcher ----------------
extern "C" void kernel_launch(void* const* d_in, const int* in_sizes, int n_in,
                              void* d_out, int out_size, void* d_ws, size_t ws_size,
                              hipStream_t stream) {
  const float* x  = (const float*)d_in[0];
  const float* Wq = (const float*)d_in[1];
  const float* Wk = (const float*)d_in[2];
  const float* Wv = (const float*)d_in[3];
  const float* Wo = (const float*)d_in[4];
  float* out = (float*)d_out;

  char* ws = (char*)d_ws;
  u16* xb    = (u16*)(ws);                          // [2048][4096]   16 MiB
  u16* wqkvF = (u16*)(ws + (16ull << 20));          // frag-order     48 MiB
  u16* woF   = (u16*)(ws + (64ull << 20));          // frag-order     32 MiB
  u16* qkvb  = (u16*)(ws + (96ull << 20));          // [2048][6144]   24 MiB
  u16* qb    = (u16*)(ws + (16ull << 20));          // QF frag-order  16 MiB (over dead wqkvF)
  u16* kfb   = (u16*)(ws + (32ull << 20));          // KF frag-order   4 MiB
  u16* vfb   = (u16*)(ws + (36ull << 20));          // VF frag-order   4 MiB
  u16* ao    = (u16*)(ws);                          // [2048][4096]   16 MiB (over xb)

  const int smem_g = 2 * 128 * 64 * 2;              // 32768 B
  hipFuncSetAttribute((const void*)&gemm_bg<192, 48, 1>,
                      hipFuncAttributeMaxDynamicSharedMemorySize, smem_g);
  hipFuncSetAttribute((const void*)&gemm_bg<128, 32, 0>,
                      hipFuncAttributeMaxDynamicSharedMemorySize, smem_g);

  // fused cast; weights written directly in frag-order
  cast_all<<<4096, 256, 0, stream>>>(x, Wq, Wk, Wv, Wo, xb, wqkvF, woF);

  // fused QKV projection: 128x192 tiles, 512 blocks = 2/CU, B via global frags
  gemm_bg<192, 48, 1><<<512, 512, smem_g, stream>>>(xb, wqkvF, qkvb, 2048, 6144, 4096);

  // Q scale = (1/sqrt(128)) * log2(e)  -> logits in base-2 domain
  rope_qk<<<(32 * 2048 * 64) / 256, 256, 0, stream>>>(qkvb, qb,  0,    0.12751741f, 1);
  rope_qk<<<(8  * 2048 * 64) / 256, 256, 0, stream>>>(qkvb, kfb, 4096, 1.0f,        1);
  vf_pack<<<512, 256, 0, stream>>>(qkvb, vfb);

  attn_fwd<<<512, 256, 0, stream>>>(qb, kfb, vfb, ao);

  // output projection: 128x128 tiles, 512 blocks = 2/CU, B via global frags
  gemm_bg<128, 32, 0><<<512, 512, smem_g, stream>>>(ao, woF, out, 2048, 4096, 4096);
}

// Round 20
// 303.075 us; speedup vs baseline: 1.4060x; 1.4060x over previous
//
#include <hip/hip_runtime.h>

typedef unsigned short u16;
typedef unsigned int u32;

using f32x4  = __attribute__((ext_vector_type(4))) float;
using f32x16 = __attribute__((ext_vector_type(16))) float;
using bf16x8 = __attribute__((ext_vector_type(8))) __bf16;

#define S_LEN 2048
#define HID_DIM 4096
#define NH 32
#define NKV 8
#define HD 128
#define QKVN 6144

__device__ __forceinline__ u16 f2b(float f) {
  union { float f; u32 u; } v; v.f = f;
  u32 r = (v.u + 0x7FFFu + ((v.u >> 16) & 1u)) >> 16;
  return (u16)r;
}
__device__ __forceinline__ float b2f(u16 b) {
  union { u32 u; float f; } v; v.u = ((u32)b) << 16;
  return v.f;
}

__device__ __forceinline__ u32 cvtpk_bf16(float lo, float hi) {
  u32 r;
  asm("v_cvt_pk_bf16_f32 %0, %1, %2" : "=v"(r) : "v"(lo), "v"(hi));
  return r;
}
__device__ __forceinline__ void plane_swap(u32& a, u32& b) {
  asm volatile("v_permlane32_swap_b32 %0, %1" : "+v"(a), "+v"(b));
}

#define AS1 __attribute__((address_space(1)))
#define AS3 __attribute__((address_space(3)))
__device__ __forceinline__ void gl_lds16(const u16* g, u16* l) {
  __builtin_amdgcn_global_load_lds((const AS1 u32*)g, (AS3 u32*)l, 16, 0, 0);
}

#define SBAR  __builtin_amdgcn_s_barrier()
#define SCHED0 __builtin_amdgcn_sched_barrier(0)
#define LGKM0 do { asm volatile("s_waitcnt lgkmcnt(0)" ::: "memory"); SCHED0; } while (0)
#define PRIO1 __builtin_amdgcn_s_setprio(1)
#define PRIO0 __builtin_amdgcn_s_setprio(0)

template <int N> __device__ __forceinline__ void waitv() {
  if constexpr (N == 0)      asm volatile("s_waitcnt vmcnt(0)" ::: "memory");
  else if constexpr (N == 6) asm volatile("s_waitcnt vmcnt(6)" ::: "memory");
  else if constexpr (N == 7) asm volatile("s_waitcnt vmcnt(7)" ::: "memory");
  else                       asm volatile("s_waitcnt vmcnt(0)" ::: "memory");
  SCHED0;
}

// ---------------- fused fp32 -> bf16 cast of all five inputs (linear) -------
#define X4T 2097152
#define Q4T 4194304
#define K4T 1048576
#define TOT4 (X4T + Q4T + K4T + K4T + Q4T)
__global__ void cast_all(const float* __restrict__ x,  const float* __restrict__ wq,
                         const float* __restrict__ wk, const float* __restrict__ wv,
                         const float* __restrict__ wo,
                         u16* __restrict__ xb, u16* __restrict__ wqkv,
                         u16* __restrict__ wo_b) {
  int i = blockIdx.x * blockDim.x + threadIdx.x;
  int stride = gridDim.x * blockDim.x;
  for (; i < TOT4; i += stride) {
    const float* src;
    uint2* dst;
    int off;
    if (i < X4T)                     { src = x;  dst = (uint2*)xb;   off = i; }
    else if (i < X4T + Q4T)          { src = wq; dst = (uint2*)wqkv; off = i - X4T; }
    else if (i < X4T + Q4T + K4T)    { src = wk; dst = (uint2*)wqkv + Q4T; off = i - X4T - Q4T; }
    else if (i < X4T + Q4T + 2*K4T)  { src = wv; dst = (uint2*)wqkv + Q4T + K4T; off = i - X4T - Q4T - K4T; }
    else                             { src = wo; dst = (uint2*)wo_b; off = i - X4T - Q4T - 2*K4T; }
    float4 v = ((const float4*)src)[off];
    uint2 o;
    o.x = (u32)f2b(v.x) | ((u32)f2b(v.y) << 16);
    o.y = (u32)f2b(v.z) | ((u32)f2b(v.w) << 16);
    dst[off] = o;
  }
}

// STAGE: CH chunks of 8KB (512 thr x 16B), XOR-swizzled source, linear LDS dest
#define STAGE(DST, SRC, CH, LDK)                                   \
  _Pragma("unroll") for (int c = 0; c < (CH); ++c) {               \
    int d_ = c * 8192 + tid * 16;                                  \
    int rw_ = d_ >> 7;                                             \
    int cb_ = (d_ & 127) ^ ((rw_ & 7) << 4);                       \
    gl_lds16((SRC) + (size_t)rw_ * (LDK) + (cb_ >> 1), (DST) + (d_ >> 1)); \
  }

// ============ GEMM: C[M,N] = A[M,K]*B[N,K]^T, 256-wide, 2-barrier K-loop ==
// (r12 verified structure — best measured: 117.7/117.6 us per projection)
#define RDA(ABUF, MLO, KS)                                                    \
  _Pragma("unroll") for (int mm = 0; mm < 4; ++mm)                            \
    af[(MLO) + mm][KS] = *(const bf16x8*)((const char*)(ABUF) +               \
      (wmo + ((MLO) + mm) * 16 + lr) * 128 + (((((KS) << 2) | lg) ^ lr7) << 4));

#define RDB(BBUF, KS)                                                         \
  _Pragma("unroll") for (int nn = 0; nn < NF; ++nn)                           \
    bfr[nn][KS] = *(const bf16x8*)((const char*)(BBUF) +                      \
      (wno + nn * 16 + lr) * 128 + (((((KS) << 2) | lg) ^ lr7) << 4));

#define MFMA_Q(MLO, KS)                                                       \
  _Pragma("unroll") for (int mm = 0; mm < 4; ++mm)                            \
  _Pragma("unroll") for (int nn = 0; nn < NF; ++nn)                           \
    acc[(MLO) + mm][nn] = __builtin_amdgcn_mfma_f32_16x16x32_bf16(            \
        af[(MLO) + mm][KS], bfr[nn][KS], acc[(MLO) + mm][nn], 0, 0, 0);

template <int BN, int WN, int CBF>
__global__ __launch_bounds__(512, 2) void gemm8p(
    const u16* __restrict__ A, const u16* __restrict__ B, void* __restrict__ Cout,
    int M, int N, int K)
{
  constexpr int BM = 256;
  constexpr int NF = WN / 16;
  constexpr int LA = BM / 64;
  constexpr int LB = BN / 64;
  constexpr int LT = LA + LB;
  extern __shared__ __align__(16) u16 smem[];
  u16* const As0 = smem;
  u16* const Bs0 = smem + 2 * BM * 64;

  const int tid  = threadIdx.x;
  const int lane = tid & 63;
  const int wave = tid >> 6;
  const int lr  = lane & 15;
  const int lg  = lane >> 4;
  const int lr7 = lane & 7;

  const int nbx = N / BN;
  const int bid = blockIdx.x;
  const int cpx = gridDim.x >> 3;
  const int swz = (bid & 7) * cpx + (bid >> 3);   // XCD swizzle (grid%8==0)
  const int bm = (swz / nbx) * BM;
  const int bn = (swz % nbx) * BN;
  const int wmo = (wave >> 2) * 128;
  const int wno = (wave & 3) * WN;

  const int NT = K >> 6;

  f32x4 acc[8][NF] = {};
  bf16x8 af[8][2], bfr[NF][2];

  const u16* aP = A + (size_t)bm * K;
  const u16* bP = B + (size_t)bn * K;

  STAGE(As0,           aP,      LA, K);
  STAGE(Bs0,           bP,      LB, K);
  STAGE(As0 + BM * 64, aP + 64, LA, K);
  STAGE(Bs0 + BN * 64, bP + 64, LB, K);
  waitv<LT>();
  SBAR; SCHED0;

  for (int t = 0; t < NT; ++t) {
    const int buf = t & 1;
    const u16* ab = As0 + buf * (BM * 64);
    const u16* bb = Bs0 + buf * (BN * 64);
    const bool st = (t + 2 < NT);

    RDA(ab, 0, 0); RDA(ab, 4, 0); RDB(bb, 0);
    LGKM0;
    PRIO1; MFMA_Q(0, 0); MFMA_Q(4, 0); PRIO0;
    RDA(ab, 0, 1); RDA(ab, 4, 1); RDB(bb, 1);
    LGKM0;
    SBAR;

    if (st) {
      STAGE(As0 + buf * (BM * 64), aP + (size_t)(t + 2) * 64, LA, K);
      STAGE(Bs0 + buf * (BN * 64), bP + (size_t)(t + 2) * 64, LB, K);
    }
    PRIO1; MFMA_Q(0, 1); MFMA_Q(4, 1); PRIO0;
    if (t + 1 < NT) {
      if (st) waitv<LT>(); else waitv<0>();
    }
    SBAR; SCHED0;
  }

#pragma unroll
  for (int m = 0; m < 8; ++m)
#pragma unroll
    for (int j = 0; j < 4; ++j) {
      int row = bm + wmo + m * 16 + lg * 4 + j;
      size_t base = (size_t)row * N + bn + wno + lr;
      if constexpr (CBF) {
        u16* C = (u16*)Cout;
#pragma unroll
        for (int nn = 0; nn < NF; ++nn) C[base + nn * 16] = f2b(acc[m][nn][j]);
      } else {
        float* C = (float*)Cout;
#pragma unroll
        for (int nn = 0; nn < NF; ++nn) C[base + nn * 16] = acc[m][nn][j];
      }
    }
}

// ---------------- RoPE; frag=0 -> [nh][S][D], frag=1 -> frag-order ----------
__global__ void rope_qk(const u16* __restrict__ qkv, u16* __restrict__ dst,
                        int col_off, float scale, int frag) {
  int idx = blockIdx.x * blockDim.x + threadIdx.x;
  int i = idx & 63;
  int s = (idx >> 6) & (S_LEN - 1);
  int h = idx >> 17;
  const u16* row = qkv + (size_t)s * QKVN + col_off + h * HD;
  float a = b2f(row[i]);
  float b = b2f(row[i + 64]);
  float invf = __expf(-(float)i * 0.14391156831212787f);  // ln(10000)/64
  float f = (float)s * invf;
  float sn, cs;
  sincosf(f, &sn, &cs);
  float o1 = (a * cs - b * sn) * scale;
  float o2 = (b * cs + a * sn) * scale;
  if (frag) {
    int qt = h * 64 + (s >> 5);
    int qq = s & 31;
    int i2 = i + 64;
    dst[((qt * 8 + (i  >> 4)) * 2 + ((i  >> 3) & 1)) * 256 + qq * 8 + (i  & 7)] = f2b(o1);
    dst[((qt * 8 + (i2 >> 4)) * 2 + ((i2 >> 3) & 1)) * 256 + qq * 8 + (i2 & 7)] = f2b(o2);
  } else {
    u16* orow = dst + ((size_t)h * S_LEN + s) * HD;
    orow[i]      = f2b(o1);
    orow[i + 64] = f2b(o2);
  }
}

// ---------------- V frag-order pack ----------------
__global__ __launch_bounds__(256) void vf_pack(const u16* __restrict__ qkv,
                                               u16* __restrict__ VF) {
  __shared__ u16 vlds[32][136];
  const int bid = blockIdx.x;          // kv*64 + t
  const int kv = bid >> 6, t = bid & 63;
  const int tid = threadIdx.x;
  const int r = tid >> 3, d0 = (tid & 7) * 16;
  const u16* src = qkv + (size_t)(t * 32 + r) * QKVN + 5120 + kv * HD + d0;
  *(bf16x8*)&vlds[r][d0]     = *(const bf16x8*)src;
  *(bf16x8*)&vlds[r][d0 + 8] = *(const bf16x8*)(src + 8);
  __syncthreads();
  u16* outt = VF + (size_t)bid * 4096;
#pragma unroll
  for (int g = 0; g < 2; ++g) {
    int G = tid + g * 256;
    int q = G & 31, dt = (G >> 5) & 3, hi2 = (G >> 7) & 1, kc = G >> 8;
    union { u16 u[8]; uint4 v; } o;
#pragma unroll
    for (int e = 0; e < 8; ++e)
      o.u[e] = vlds[kc * 16 + hi2 * 8 + e][dt * 32 + q];
    *(uint4*)&outt[G * 8] = o.v;
  }
}

// ---------------- flash attention: all-frag-order (r12-verified) ----------
__global__ __launch_bounds__(256, 2) void attn_fwd(
    const u16* __restrict__ QF,  // frag-order Q (pre-scaled log2(e)/sqrt(D))
    const u16* __restrict__ KF,  // frag-order K
    const u16* __restrict__ VF,  // frag-order V
    u16* __restrict__ Out)       // [S][H*D]
{
  const int tid  = threadIdx.x;
  const int lane = tid & 63;
  const int wv   = tid >> 6;
  const int q31  = lane & 31;
  const int hi   = lane >> 5;
  const int bid  = blockIdx.x;
  const int kvh  = bid & 7;
  const int qi   = 63 - (bid >> 3);       // heavy blocks first
  const int q0   = qi * 32;
  const int h    = kvh * 4 + wv;
  const int nt   = qi + 1;

  const u16* kbase = KF + (size_t)kvh * 64 * 4096 + hi * 256  + q31 * 8;
  const u16* vbase = VF + (size_t)kvh * 64 * 4096 + hi * 1024 + q31 * 8;

  bf16x8 qf[8];
  const u16* qfp = QF + (size_t)(h * 64 + qi) * 4096 + hi * 256 + q31 * 8;
#pragma unroll
  for (int dc = 0; dc < 8; ++dc)
    qf[dc] = *(const bf16x8*)(qfp + dc * 512);

  f32x16 o0 = {}, o1 = {}, o2 = {}, o3 = {};
  float m = -1e30f, lsum = 0.f;

  for (int t = 0; t < nt; ++t) {
    SBAR;

    bf16x8 kf[8];
    const u16* kfp = kbase + (size_t)t * 4096;
#pragma unroll
    for (int dc = 0; dc < 8; ++dc)
      kf[dc] = *(const bf16x8*)(kfp + dc * 512);

    bf16x8 vf[8];
    const u16* vfp = vbase + (size_t)t * 4096;
#pragma unroll
    for (int i = 0; i < 8; ++i)
      vf[i] = *(const bf16x8*)(vfp + (i & 1) * 2048 + (i >> 1) * 256);

    f32x16 st = {};
    PRIO1;
#pragma unroll
    for (int dc = 0; dc < 8; ++dc)
      st = __builtin_amdgcn_mfma_f32_32x32x16_bf16(kf[dc], qf[dc], st, 0, 0, 0);
    PRIO0;

    if (t == nt - 1) {
#pragma unroll
      for (int r = 0; r < 16; ++r) {
        int kk = (r & 3) + 8 * (r >> 2) + 4 * hi;
        if (kk > q31) st[r] = -1e30f;
      }
    }

    float a0 = fmaxf(st[0], st[1]),   a1 = fmaxf(st[2], st[3]);
    float a2 = fmaxf(st[4], st[5]),   a3 = fmaxf(st[6], st[7]);
    float a4 = fmaxf(st[8], st[9]),   a5 = fmaxf(st[10], st[11]);
    float a6 = fmaxf(st[12], st[13]), a7 = fmaxf(st[14], st[15]);
    a0 = fmaxf(a0, a1); a2 = fmaxf(a2, a3); a4 = fmaxf(a4, a5); a6 = fmaxf(a6, a7);
    float pmax = fmaxf(fmaxf(a0, a2), fmaxf(a4, a6));
    pmax = fmaxf(pmax, __shfl_xor(pmax, 32));

    if (__any(pmax > m + 8.f)) {
      float mn = fmaxf(m, pmax);
      float sf = exp2f(m - mn);
      m = mn;
      lsum *= sf;
#pragma unroll
      for (int r = 0; r < 16; ++r) { o0[r] *= sf; o1[r] *= sf; o2[r] *= sf; o3[r] *= sf; }
    }

    float ev[16];
#pragma unroll
    for (int r = 0; r < 16; ++r) ev[r] = exp2f(st[r] - m);
    float s0 = (ev[0] + ev[1]) + (ev[2] + ev[3]);
    float s1 = (ev[4] + ev[5]) + (ev[6] + ev[7]);
    float s2 = (ev[8] + ev[9]) + (ev[10] + ev[11]);
    float s3 = (ev[12] + ev[13]) + (ev[14] + ev[15]);
    float ps = (s0 + s1) + (s2 + s3);
    ps += __shfl_xor(ps, 32);
    lsum += ps;

    u32 c0 = cvtpk_bf16(ev[0],  ev[1]),  c1 = cvtpk_bf16(ev[2],  ev[3]);
    u32 c2 = cvtpk_bf16(ev[4],  ev[5]),  c3 = cvtpk_bf16(ev[6],  ev[7]);
    u32 c4 = cvtpk_bf16(ev[8],  ev[9]),  c5 = cvtpk_bf16(ev[10], ev[11]);
    u32 c6 = cvtpk_bf16(ev[12], ev[13]), c7 = cvtpk_bf16(ev[14], ev[15]);
    plane_swap(c0, c2);
    plane_swap(c1, c3);
    plane_swap(c4, c6);
    plane_swap(c5, c7);
    union { u32 u[4]; bf16x8 v; } pb0u, pb1u;
    pb0u.u[0] = c0; pb0u.u[1] = c1; pb0u.u[2] = c2; pb0u.u[3] = c3;
    pb1u.u[0] = c4; pb1u.u[1] = c5; pb1u.u[2] = c6; pb1u.u[3] = c7;

    PRIO1;
    o0 = __builtin_amdgcn_mfma_f32_32x32x16_bf16(vf[0], pb0u.v, o0, 0, 0, 0);
    o1 = __builtin_amdgcn_mfma_f32_32x32x16_bf16(vf[2], pb0u.v, o1, 0, 0, 0);
    o2 = __builtin_amdgcn_mfma_f32_32x32x16_bf16(vf[4], pb0u.v, o2, 0, 0, 0);
    o3 = __builtin_amdgcn_mfma_f32_32x32x16_bf16(vf[6], pb0u.v, o3, 0, 0, 0);
    o0 = __builtin_amdgcn_mfma_f32_32x32x16_bf16(vf[1], pb1u.v, o0, 0, 0, 0);
    o1 = __builtin_amdgcn_mfma_f32_32x32x16_bf16(vf[3], pb1u.v, o1, 0, 0, 0);
    o2 = __builtin_amdgcn_mfma_f32_32x32x16_bf16(vf[5], pb1u.v, o2, 0, 0, 0);
    o3 = __builtin_amdgcn_mfma_f32_32x32x16_bf16(vf[7], pb1u.v, o3, 0, 0, 0);
    PRIO0;
  }

  float inv = 1.0f / lsum;
  u16* orow = Out + (size_t)(q0 + q31) * (NH * HD) + h * HD;
#pragma unroll
  for (int dt = 0; dt < 4; ++dt) {
    const f32x16& oo = dt == 0 ? o0 : dt == 1 ? o1 : dt == 2 ? o2 : o3;
#pragma unroll
    for (int g = 0; g < 4; ++g) {
      ushort4 pk;
      pk.x = f2b(oo[g * 4 + 0] * inv);
      pk.y = f2b(oo[g * 4 + 1] * inv);
      pk.z = f2b(oo[g * 4 + 2] * inv);
      pk.w = f2b(oo[g * 4 + 3] * inv);
      *(ushort4*)&orow[dt * 32 + 8 * g + 4 * hi] = pk;
    }
  }
}

// ---------------- launcher ----------------
extern "C" void kernel_launch(void* const* d_in, const int* in_sizes, int n_in,
                              void* d_out, int out_size, void* d_ws, size_t ws_size,
                              hipStream_t stream) {
  const float* x  = (const float*)d_in[0];
  const float* Wq = (const float*)d_in[1];
  const float* Wk = (const float*)d_in[2];
  const float* Wv = (const float*)d_in[3];
  const float* Wo = (const float*)d_in[4];
  float* out = (float*)d_out;

  char* ws = (char*)d_ws;
  u16* xb   = (u16*)(ws);                           // [2048][4096]   16 MiB
  u16* wqkv = (u16*)(ws + (16ull << 20));           // [6144][4096]   48 MiB
  u16* wo_b = (u16*)(ws + (64ull << 20));           // [4096][4096]   32 MiB
  u16* qkvb = (u16*)(ws + (96ull << 20));           // [2048][6144]   24 MiB
  u16* qb   = (u16*)(ws + (16ull << 20));           // QF frag-order  16 MiB (over dead wqkv)
  u16* kfb  = (u16*)(ws + (32ull << 20));           // KF frag-order   4 MiB
  u16* vfb  = (u16*)(ws + (36ull << 20));           // VF frag-order   4 MiB
  u16* ao   = (u16*)(ws);                           // [2048][4096]   16 MiB (over xb)

  const int smem_q = (256 + 192) * 256;  // 114688 B
  const int smem_o = (256 + 128) * 256;  //  98304 B
  hipFuncSetAttribute((const void*)&gemm8p<192, 48, 1>,
                      hipFuncAttributeMaxDynamicSharedMemorySize, smem_q);
  hipFuncSetAttribute((const void*)&gemm8p<128, 32, 0>,
                      hipFuncAttributeMaxDynamicSharedMemorySize, smem_o);

  // fused cast of all 5 inputs (one dispatch, linear writes)
  cast_all<<<4096, 256, 0, stream>>>(x, Wq, Wk, Wv, Wo, xb, wqkv, wo_b);

  // fused QKV projection: 256x192 tiles, 256 blocks
  gemm8p<192, 48, 1><<<256, 512, smem_q, stream>>>(xb, wqkv, qkvb, 2048, 6144, 4096);

  // Q scale = (1/sqrt(128)) * log2(e)  -> logits in base-2 domain
  rope_qk<<<(32 * 2048 * 64) / 256, 256, 0, stream>>>(qkvb, qb,  0,    0.12751741f, 1);
  rope_qk<<<(8  * 2048 * 64) / 256, 256, 0, stream>>>(qkvb, kfb, 4096, 1.0f,        1);
  vf_pack<<<512, 256, 0, stream>>>(qkvb, vfb);

  attn_fwd<<<512, 256, 0, stream>>>(qb, kfb, vfb, ao);

  // output projection: 256x128 tiles, 256 blocks
  gemm8p<128, 32, 0><<<256, 512, smem_o, stream>>>(ao, wo_b, out, 2048, 4096, 4096);
}